// Round 9
// baseline (699.803 us; speedup 1.0000x reference)
//
#include <hip/hip_runtime.h>
#include <math.h>

#define NEG_SLOPE 0.2f
#define BN_EPS 1e-5f
#define LOG2E 1.44269504f

typedef _Float16 f16x8 __attribute__((ext_vector_type(8)));
typedef float f32x4 __attribute__((ext_vector_type(4)));
typedef _Float16 h2 __attribute__((ext_vector_type(2)));

union F8 { f16x8 v; h2 h[4]; _Float16 s[8]; uint4 u; };

__device__ __forceinline__ void async_copy16(const void* g, void* l) {
  __builtin_amdgcn_global_load_lds(
      (const __attribute__((address_space(1))) void*)g,
      (__attribute__((address_space(3))) void*)l, 16, 0, 0);
}

__device__ __forceinline__ unsigned int pack2f(float a, float b) {
  union { unsigned int u; _Float16 h[2]; } c;
  c.h[0] = (_Float16)a; c.h[1] = (_Float16)b; return c.u;
}

__device__ __forceinline__ float fdot2f(h2 a, h2 b, float c) {
#if __has_builtin(__builtin_amdgcn_fdot2)
  return __builtin_amdgcn_fdot2(a, b, c, false);
#else
  return fmaf((float)a[0], (float)b[0], fmaf((float)a[1], (float)b[1], c));
#endif
}

// DPP butterfly add within quads (pure VALU, no LDS pipe).
template <int CTRL>
__device__ __forceinline__ float dpp_xadd(float x) {
  int yi = __builtin_amdgcn_mov_dpp(__builtin_bit_cast(int, x), CTRL, 0xF, 0xF, true);
  return x + __builtin_bit_cast(float, yi);
}

// ---------------- fused prep: f2h + weight transpose/concat + att/BN fold ------------
__global__ __launch_bounds__(256) void k_prep_all(
    const float* __restrict__ x, unsigned int* __restrict__ x16u, int n2,
    const float* __restrict__ Wl1, const float* __restrict__ Wr1,
    const float* __restrict__ Wl2, const float* __restrict__ Wr2,
    const float* __restrict__ Wl3, const float* __restrict__ Wr3,
    int Cin, int Hm, int Cout,
    _Float16* __restrict__ WT1, _Float16* __restrict__ WT2, _Float16* __restrict__ WT3,
    const float* __restrict__ att1, const float* __restrict__ att2, const float* __restrict__ att3,
    const float* __restrict__ b1, const float* __restrict__ g1, const float* __restrict__ bb1,
    const float* __restrict__ m1, const float* __restrict__ v1,
    const float* __restrict__ b2, const float* __restrict__ g2, const float* __restrict__ bb2,
    const float* __restrict__ m2, const float* __restrict__ v2,
    _Float16* __restrict__ a16_1, _Float16* __restrict__ a16_2, _Float16* __restrict__ a16_3,
    float* __restrict__ sc1, float* __restrict__ sh1,
    float* __restrict__ sc2, float* __restrict__ sh2) {
  int i = blockIdx.x * 256 + threadIdx.x;
  if (i < n2) {
    float2 v = reinterpret_cast<const float2*>(x)[i];
    x16u[i] = pack2f(v.x, v.y);
    return;
  }
  i -= n2;
  int w1 = 2 * Hm * Cin, w2 = 2 * Hm * Hm, w3 = 2 * Cout * Hm;
  if (i < w1) {
    int c = i / Cin, k = i % Cin;
    float v = (c < Hm) ? Wl1[(size_t)k * Hm + c] : Wr1[(size_t)k * Hm + (c - Hm)];
    WT1[i] = (_Float16)v;
    return;
  }
  i -= w1;
  if (i < w2) {
    int c = i / Hm, k = i % Hm;
    float v = (c < Hm) ? Wl2[(size_t)k * Hm + c] : Wr2[(size_t)k * Hm + (c - Hm)];
    WT2[i] = (_Float16)v;
    return;
  }
  i -= w2;
  if (i < w3) {
    int c = i / Hm, k = i % Hm;
    float v = (c < Cout) ? Wl3[(size_t)k * Cout + c] : Wr3[(size_t)k * Cout + (c - Cout)];
    WT3[i] = (_Float16)v;
    return;
  }
  i -= w3;
  if (i < 256) {
    int c = i;
    a16_1[c] = (_Float16)(att1[c] * LOG2E);
    a16_2[c] = (_Float16)(att2[c] * LOG2E);
    if (c < 128) a16_3[c] = (_Float16)(att3[c] * LOG2E);
    float s = g1[c] * rsqrtf(v1[c] + BN_EPS);
    sc1[c] = s; sh1[c] = (b1[c] - m1[c]) * s + bb1[c];
    s = g2[c] * rsqrtf(v2[c] + BN_EPS);
    sc2[c] = s; sh2[c] = (b2[c] - m2[c]) * s + bb2[c];
  }
}

// ---------------- CSR build (group edges by dst, self-loops appended) ----------------
__global__ void k_count(const int* __restrict__ ei, int E, int N, int* __restrict__ deg) {
  int e = blockIdx.x * blockDim.x + threadIdx.x;
  int T = E + N;
  if (e >= T) return;
  int d = (e < E) ? ei[E + e] : (e - E);
  atomicAdd(&deg[d], 1);
}

__global__ __launch_bounds__(256) void k_bsum(const int* __restrict__ deg, int N,
                                              int* __restrict__ bsum) {
  int t = threadIdx.x;
  int i = blockIdx.x * 256 + t;
  int v = (i < N) ? deg[i] : 0;
  #pragma unroll
  for (int off = 32; off > 0; off >>= 1) v += __shfl_xor(v, off, 64);
  __shared__ int ws[4];
  if ((t & 63) == 0) ws[t >> 6] = v;
  __syncthreads();
  if (t == 0) bsum[blockIdx.x] = ws[0] + ws[1] + ws[2] + ws[3];
}

__global__ __launch_bounds__(1024) void k_bscan(int* __restrict__ bsum, int nb, int N,
                                                int* __restrict__ offs) {
  int t = threadIdx.x;
  int lane = t & 63, w = t >> 6;
  int v = (t < nb) ? bsum[t] : 0;
  int val = v;
  #pragma unroll
  for (int off = 1; off < 64; off <<= 1) {
    int x = __shfl_up(val, off, 64);
    if (lane >= off) val += x;
  }
  __shared__ int ws[16];
  if (lane == 63) ws[w] = val;
  __syncthreads();
  if (w == 0) {
    int s = (lane < 16) ? ws[lane] : 0;
    #pragma unroll
    for (int off = 1; off < 16; off <<= 1) {
      int x = __shfl_up(s, off, 64);
      if (lane >= off) s += x;
    }
    if (lane < 16) ws[lane] = s;
  }
  __syncthreads();
  int excl = (w > 0 ? ws[w - 1] : 0) + val - v;
  if (t < nb) bsum[t] = excl;
  if (t == nb - 1 && offs) offs[N] = excl + v;
}

__global__ __launch_bounds__(256) void k_boffs(const int* __restrict__ deg, int N,
                                               const int* __restrict__ bpre,
                                               int* __restrict__ offs, int* __restrict__ cursor) {
  int t = threadIdx.x;
  int i = blockIdx.x * 256 + t;
  int lane = t & 63, w = t >> 6;
  int v = (i < N) ? deg[i] : 0;
  int val = v;
  #pragma unroll
  for (int off = 1; off < 64; off <<= 1) {
    int x = __shfl_up(val, off, 64);
    if (lane >= off) val += x;
  }
  __shared__ int ws[4];
  if (lane == 63) ws[w] = val;
  __syncthreads();
  int wo = 0;
  #pragma unroll
  for (int k = 0; k < 4; ++k) if (k < w) wo += ws[k];
  int excl = bpre[blockIdx.x] + wo + val - v;
  if (i < N) { offs[i] = excl; cursor[i] = excl; }
}

__global__ void k_scatter(const int* __restrict__ ei, int E, int N,
                          int* __restrict__ cursor, int* __restrict__ csr_src) {
  int e = blockIdx.x * blockDim.x + threadIdx.x;
  int T = E + N;
  if (e < 32) csr_src[T + e] = 0;  // sentinels for prefetch
  if (e >= T) return;
  int s, d;
  if (e < E) { s = ei[e]; d = ei[E + e]; } else { s = d = e - E; }
  int pos = atomicAdd(&cursor[d], 1);
  csr_src[pos] = s;
}

// ---------------- degree-descending node order (bucket sort) ----------------
__global__ void k_hist(const int* __restrict__ deg, int N, int* __restrict__ hist) {
  int i = blockIdx.x * blockDim.x + threadIdx.x;
  if (i >= N) return;
  int b = 1023 - min(deg[i], 1023);      // reversed -> descending degree
  atomicAdd(&hist[b], 1);
}

__global__ void k_horder(const int* __restrict__ deg, int N,
                         int* __restrict__ hcur, int* __restrict__ order) {
  int i = blockIdx.x * blockDim.x + threadIdx.x;
  if (i >= N) return;
  int b = 1023 - min(deg[i], 1023);
  int pos = atomicAdd(&hcur[b], 1);
  order[pos] = i;
}

// ---------------- fp16 MFMA GEMM: C[M,Ntot] = A[M,K] @ BT[Ntot,K]^T ----------------
// 128x256 tile, BK=64, 512 threads (8 waves, 2x4 of 64x64). Counted-vmcnt pipeline.
__global__ __launch_bounds__(512) void k_hgemm(const _Float16* __restrict__ A,
                                               const _Float16* __restrict__ BT,
                                               _Float16* __restrict__ C,
                                               int M, int Ntot, int K) {
  __shared__ _Float16 As[2][128 * 64];
  __shared__ _Float16 Bs[2][256 * 64];
  const int t = threadIdx.x;
  const int lane = t & 63, w = t >> 6;
  const int wr = w >> 2, wc = w & 3;
  const int bm0 = blockIdx.x * 128, bn0 = blockIdx.y * 256;
  f32x4 acc[4][4] = {};
  const int nkt = K >> 6;

  auto stage = [&](int b, int kt) {
    #pragma unroll
    for (int i = 0; i < 2; ++i) {
      int q = i * 512 + t;                 // A: 1024 slots
      int row = q >> 3, sl = q & 7;
      int ssrc = sl ^ (row & 7);
      int ga = bm0 + row; if (ga >= M) ga = M - 1;
      async_copy16(&A[(size_t)ga * K + kt * 64 + ssrc * 8], &As[b][q * 8]);
    }
    #pragma unroll
    for (int i = 0; i < 4; ++i) {
      int q = i * 512 + t;                 // B: 2048 slots
      int row = q >> 3, sl = q & 7;
      int ssrc = sl ^ (row & 7);
      async_copy16(&BT[(size_t)(bn0 + row) * K + kt * 64 + ssrc * 8], &Bs[b][q * 8]);
    }
  };

  stage(0, 0);
  for (int kt = 0; kt < nkt; ++kt) {
    int cur = kt & 1;
    if (kt + 1 < nkt) {
      stage(cur ^ 1, kt + 1);
      asm volatile("s_waitcnt vmcnt(6)" ::: "memory");   // prev stage drained
    } else {
      asm volatile("s_waitcnt vmcnt(0)" ::: "memory");
    }
    __builtin_amdgcn_s_barrier();
    #pragma unroll
    for (int ks = 0; ks < 2; ++ks) {
      f16x8 a[4], b[4];
      const int sl = ks * 4 + (lane >> 4);
      #pragma unroll
      for (int mi = 0; mi < 4; ++mi) {
        int row = wr * 64 + mi * 16 + (lane & 15);
        a[mi] = *(const f16x8*)&As[cur][(row * 8 + (sl ^ (row & 7))) * 8];
      }
      #pragma unroll
      for (int ni = 0; ni < 4; ++ni) {
        int row = wc * 64 + ni * 16 + (lane & 15);
        b[ni] = *(const f16x8*)&Bs[cur][(row * 8 + (sl ^ (row & 7))) * 8];
      }
      #pragma unroll
      for (int mi = 0; mi < 4; ++mi)
        #pragma unroll
        for (int ni = 0; ni < 4; ++ni)
          acc[mi][ni] = __builtin_amdgcn_mfma_f32_16x16x32_f16(a[mi], b[ni], acc[mi][ni], 0, 0, 0);
    }
    __builtin_amdgcn_s_barrier();
  }
  const int r0 = (lane >> 4) * 4;
  const int cc = lane & 15;
  #pragma unroll
  for (int mi = 0; mi < 4; ++mi) {
    #pragma unroll
    for (int r = 0; r < 4; ++r) {
      int row = bm0 + wr * 64 + mi * 16 + r0 + r;
      if (row >= M) continue;
      #pragma unroll
      for (int ni = 0; ni < 4; ++ni) {
        int col = bn0 + wc * 64 + ni * 16 + cc;
        C[(size_t)row * Ntot + col] = (_Float16)acc[mi][ni][r];
      }
    }
  }
}

// ---------------- fused GATv2 edge phase, H=4, F=64 (Hm=256) ----------------
// 4 nodes / 256-thread block (1 wave/node, degree-sorted order); 16 ch/lane ->
// 4 edges/iteration; head = quad; 1-deep prefetch; exp2-domain online softmax.
__global__ __launch_bounds__(256) void k_gat4(
    const _Float16* __restrict__ xlr,      // [N][512]: xl|xr, row = 1024 B
    const _Float16* __restrict__ att16,    // [256], pre-scaled by log2e
    const float* __restrict__ sc, const float* __restrict__ sh,
    const int* __restrict__ offs, const int* __restrict__ csr,
    const int* __restrict__ order,
    int N, _Float16* __restrict__ hout) {  // [N][256]
  const int idx = blockIdx.x * 4 + (threadIdx.x >> 6);
  if (idx >= N) return;
  const int n = order[idx];
  const int lane = threadIdx.x & 63;
  const int sub = lane & 15;
  const int qi = lane >> 4;
  const unsigned subB = (unsigned)sub << 5;
  const char* __restrict__ xc = (const char*)xlr;

  F8 at0, at1, xr0, xr1;
  at0.u = *(const uint4*)((const char*)att16 + subB);
  at1.u = *(const uint4*)((const char*)att16 + subB + 16);
  {
    unsigned xro = (unsigned)n * 1024u + 512u + subB;
    xr0.u = *(const uint4*)(xc + xro);
    xr1.u = *(const uint4*)(xc + xro + 16);
  }
  const h2 k02 = {(_Float16)NEG_SLOPE, (_Float16)NEG_SLOPE};
  const int j0 = offs[n], j1 = offs[n + 1];

  float m = -INFINITY, l = 0.f;
  float acc[16];
  #pragma unroll
  for (int i = 0; i < 16; ++i) acc[i] = 0.f;

  unsigned oA = (unsigned)csr[j0 + qi] * 1024u + subB;
  unsigned oB = (unsigned)csr[j0 + 4 + qi] * 1024u + subB;
  F8 v0, v1;
  v0.u = *(const uint4*)(xc + oA);
  v1.u = *(const uint4*)(xc + oA + 16);

  for (int j = j0; j < j1; j += 4) {
    F8 n0, n1;
    n0.u = *(const uint4*)(xc + oB);          // prefetch next 4 edges
    n1.u = *(const uint4*)(xc + oB + 16);
    oB = (unsigned)csr[j + 8 + qi] * 1024u + subB;

    float e = 0.f;
    #pragma unroll
    for (int r = 0; r < 4; ++r) {
      h2 s0 = v0.h[r] + xr0.h[r];
      s0 = __builtin_elementwise_max(s0, s0 * k02);
      e = fdot2f(s0, at0.h[r], e);
      h2 s1 = v1.h[r] + xr1.h[r];
      s1 = __builtin_elementwise_max(s1, s1 * k02);
      e = fdot2f(s1, at1.h[r], e);
    }
    e = dpp_xadd<0xB1>(e);
    e = dpp_xadd<0x4E>(e);
    if (j + qi >= j1) e = -1e30f;             // tail mask

    if (__any(e > m + 11.5f)) {               // defer-max (log2 units)
      float mc = fmaxf(m, e);
      mc = fmaxf(mc, __shfl_xor(mc, 16, 64));
      mc = fmaxf(mc, __shfl_xor(mc, 32, 64));
      float c0 = exp2f(m - mc);
      l *= c0;
      #pragma unroll
      for (int i = 0; i < 16; ++i) acc[i] *= c0;
      m = mc;
    }
    float p = exp2f(e - m);
    l += p;
    #pragma unroll
    for (int i = 0; i < 8; ++i) acc[i] = fmaf(p, (float)v0.s[i], acc[i]);
    #pragma unroll
    for (int i = 0; i < 8; ++i) acc[8 + i] = fmaf(p, (float)v1.s[i], acc[8 + i]);
    v0 = n0; v1 = n1;
  }
  // merge quarters
  l += __shfl_xor(l, 16, 64);
  l += __shfl_xor(l, 32, 64);
  #pragma unroll
  for (int i = 0; i < 16; ++i) {
    acc[i] += __shfl_xor(acc[i], 16, 64);
    acc[i] += __shfl_xor(acc[i], 32, 64);
  }
  if (qi == 0) {
    float inv = 1.f / l;
    const float4* sc4 = (const float4*)sc;
    const float4* sh4 = (const float4*)sh;
    float ov[16];
    #pragma unroll
    for (int k = 0; k < 4; ++k) {
      float4 s4 = sc4[4 * sub + k], t4 = sh4[4 * sub + k];
      ov[4 * k + 0] = acc[4 * k + 0] * inv * s4.x + t4.x;
      ov[4 * k + 1] = acc[4 * k + 1] * inv * s4.y + t4.y;
      ov[4 * k + 2] = acc[4 * k + 2] * inv * s4.z + t4.z;
      ov[4 * k + 3] = acc[4 * k + 3] * inv * s4.w + t4.w;
    }
    #pragma unroll
    for (int i = 0; i < 16; ++i) ov[i] = ov[i] > 0.f ? ov[i] : (__expf(ov[i]) - 1.f);
    F8 o0h, o1h;
    #pragma unroll
    for (int i = 0; i < 8; ++i) { o0h.s[i] = (_Float16)ov[i]; o1h.s[i] = (_Float16)ov[8 + i]; }
    F8* ob = (F8*)hout;
    ob[(size_t)n * 32 + 2 * sub] = o0h;
    ob[(size_t)n * 32 + 2 * sub + 1] = o1h;
  }
}

// ---------------- fused GATv2 edge phase, H=1, F=128 (layer 3) ----------------
__global__ __launch_bounds__(256) void k_gat1(
    const _Float16* __restrict__ xlr,      // [N][256]: xl|xr, row = 512 B
    const _Float16* __restrict__ att16,    // [128], pre-scaled by log2e
    const float* __restrict__ bias,        // [128]
    const int* __restrict__ offs, const int* __restrict__ csr,
    const int* __restrict__ order,
    int N, float* __restrict__ out) {      // [N][128] fp32
  const int idx = blockIdx.x * 4 + (threadIdx.x >> 6);
  if (idx >= N) return;
  const int n = order[idx];
  const int lane = threadIdx.x & 63;
  const int sub = lane & 7;
  const int gi = lane >> 3;
  const unsigned subB = (unsigned)sub << 5;
  const char* __restrict__ xc = (const char*)xlr;

  F8 at0, at1, xr0, xr1;
  at0.u = *(const uint4*)((const char*)att16 + subB);
  at1.u = *(const uint4*)((const char*)att16 + subB + 16);
  {
    unsigned xro = (unsigned)n * 512u + 256u + subB;
    xr0.u = *(const uint4*)(xc + xro);
    xr1.u = *(const uint4*)(xc + xro + 16);
  }
  const h2 k02 = {(_Float16)NEG_SLOPE, (_Float16)NEG_SLOPE};
  const int j0 = offs[n], j1 = offs[n + 1];

  float m = -INFINITY, l = 0.f;
  float acc[16];
  #pragma unroll
  for (int i = 0; i < 16; ++i) acc[i] = 0.f;

  unsigned oA = (unsigned)csr[j0 + gi] * 512u + subB;
  unsigned oB = (unsigned)csr[j0 + 8 + gi] * 512u + subB;
  F8 v0, v1;
  v0.u = *(const uint4*)(xc + oA);
  v1.u = *(const uint4*)(xc + oA + 16);

  for (int j = j0; j < j1; j += 8) {
    F8 n0, n1;
    n0.u = *(const uint4*)(xc + oB);
    n1.u = *(const uint4*)(xc + oB + 16);
    oB = (unsigned)csr[j + 16 + gi] * 512u + subB;

    float e = 0.f;
    #pragma unroll
    for (int r = 0; r < 4; ++r) {
      h2 s0 = v0.h[r] + xr0.h[r];
      s0 = __builtin_elementwise_max(s0, s0 * k02);
      e = fdot2f(s0, at0.h[r], e);
      h2 s1 = v1.h[r] + xr1.h[r];
      s1 = __builtin_elementwise_max(s1, s1 * k02);
      e = fdot2f(s1, at1.h[r], e);
    }
    e = dpp_xadd<0xB1>(e);
    e = dpp_xadd<0x4E>(e);
    e += __shfl_xor(e, 4, 64);
    if (j + gi >= j1) e = -1e30f;

    if (__any(e > m + 11.5f)) {
      float mc = fmaxf(m, e);
      mc = fmaxf(mc, __shfl_xor(mc, 8, 64));
      mc = fmaxf(mc, __shfl_xor(mc, 16, 64));
      mc = fmaxf(mc, __shfl_xor(mc, 32, 64));
      float c0 = exp2f(m - mc);
      l *= c0;
      #pragma unroll
      for (int i = 0; i < 16; ++i) acc[i] *= c0;
      m = mc;
    }
    float p = exp2f(e - m);
    l += p;
    #pragma unroll
    for (int i = 0; i < 8; ++i) acc[i] = fmaf(p, (float)v0.s[i], acc[i]);
    #pragma unroll
    for (int i = 0; i < 8; ++i) acc[8 + i] = fmaf(p, (float)v1.s[i], acc[8 + i]);
    v0 = n0; v1 = n1;
  }
  l += __shfl_xor(l, 8, 64);
  l += __shfl_xor(l, 16, 64);
  l += __shfl_xor(l, 32, 64);
  #pragma unroll
  for (int i = 0; i < 16; ++i) {
    acc[i] += __shfl_xor(acc[i], 8, 64);
    acc[i] += __shfl_xor(acc[i], 16, 64);
    acc[i] += __shfl_xor(acc[i], 32, 64);
  }
  if (gi == 0) {
    float inv = 1.f / l;
    const float4* b4 = (const float4*)bias;
    float4* ob = (float4*)out;
    #pragma unroll
    for (int k = 0; k < 4; ++k) {
      float4 bb = b4[4 * sub + k];
      float4 o;
      o.x = acc[4 * k + 0] * inv + bb.x;
      o.y = acc[4 * k + 1] * inv + bb.y;
      o.z = acc[4 * k + 2] * inv + bb.z;
      o.w = acc[4 * k + 3] * inv + bb.w;
      ob[(size_t)n * 32 + 4 * sub + k] = o;
    }
  }
}

extern "C" void kernel_launch(void* const* d_in, const int* in_sizes, int n_in,
                              void* d_out, int out_size, void* d_ws, size_t ws_size,
                              hipStream_t stream) {
  const float* x    = (const float*)d_in[0];
  const int*   ei   = (const int*)d_in[1];
  const float* Wl1  = (const float*)d_in[2];
  const float* Wr1  = (const float*)d_in[3];
  const float* att1 = (const float*)d_in[4];
  const float* b1   = (const float*)d_in[5];
  const float* bn1g = (const float*)d_in[6];
  const float* bn1b = (const float*)d_in[7];
  const float* bn1m = (const float*)d_in[8];
  const float* bn1v = (const float*)d_in[9];
  const float* Wl2  = (const float*)d_in[10];
  const float* Wr2  = (const float*)d_in[11];
  const float* att2 = (const float*)d_in[12];
  const float* b2   = (const float*)d_in[13];
  const float* bn2g = (const float*)d_in[14];
  const float* bn2b = (const float*)d_in[15];
  const float* bn2m = (const float*)d_in[16];
  const float* bn2v = (const float*)d_in[17];
  const float* Wl3  = (const float*)d_in[18];
  const float* Wr3  = (const float*)d_in[19];
  const float* att3 = (const float*)d_in[20];
  const float* b3   = (const float*)d_in[21];

  const int Hm   = in_sizes[5];          // 256
  const int Cout = in_sizes[21];         // 128
  const int Cin  = in_sizes[2] / Hm;     // 128
  const int N    = in_sizes[0] / Cin;    // 50000
  const int E    = in_sizes[1] / 2;      // 800000
  const int T    = E + N;

  _Float16* x16 = (_Float16*)d_ws;                 // N*Cin
  _Float16* h   = x16 + (size_t)N * Cin;           // N*Hm
  _Float16* xlr = h + (size_t)N * Hm;              // N*2*Hm
  _Float16* WT1 = xlr + (size_t)N * 2 * Hm;        // (2*Hm)*Cin
  _Float16* WT2 = WT1 + (size_t)2 * Hm * Cin;      // (2*Hm)*Hm
  _Float16* WT3 = WT2 + (size_t)2 * Hm * Hm;       // (2*Cout)*Hm
  _Float16* a16_1 = WT3 + (size_t)2 * Cout * Hm;   // 256
  _Float16* a16_2 = a16_1 + 256;                   // 256
  _Float16* a16_3 = a16_2 + 256;                   // 128
  float* sc1 = (float*)(a16_3 + 128);              // 256
  float* sh1 = sc1 + 256;
  float* sc2 = sh1 + 256;
  float* sh2 = sc2 + 256;
  int* deg    = (int*)(sh2 + 256);                 // N
  int* offs   = deg + N;                           // N+1
  int* cursor = offs + N + 1;                      // N
  int* csr    = cursor + N;                        // T+32 (sentinels)
  int* bsum   = csr + T + 32;                      // nb
  int* hist   = bsum + (N + 255) / 256;            // 1024
  int* order  = hist + 1024;                       // N

  const int nb = (N + 255) / 256;

  // --- CSR build by dst (hierarchical scan) + degree-descending node order ---
  hipMemsetAsync(deg, 0, (size_t)N * sizeof(int), stream);
  hipMemsetAsync(hist, 0, 1024 * sizeof(int), stream);
  k_count<<<(T + 255) / 256, 256, 0, stream>>>(ei, E, N, deg);
  k_bsum<<<nb, 256, 0, stream>>>(deg, N, bsum);
  k_bscan<<<1, 1024, 0, stream>>>(bsum, nb, N, offs);
  k_boffs<<<nb, 256, 0, stream>>>(deg, N, bsum, offs, cursor);
  k_scatter<<<(T + 255) / 256, 256, 0, stream>>>(ei, E, N, cursor, csr);
  k_hist<<<(N + 255) / 256, 256, 0, stream>>>(deg, N, hist);
  k_bscan<<<1, 1024, 0, stream>>>(hist, 1024, 0, (int*)nullptr);
  k_horder<<<(N + 255) / 256, 256, 0, stream>>>(deg, N, hist, order);

  // --- fused prep: x->fp16, weights->fp16 transposed concat, att/BN folds ---
  int n2 = N * Cin / 2;
  int wtot = 2 * Hm * Cin + 2 * Hm * Hm + 2 * Cout * Hm;
  int ptot = n2 + wtot + 256;
  k_prep_all<<<(ptot + 255) / 256, 256, 0, stream>>>(
      x, (unsigned int*)x16, n2,
      Wl1, Wr1, Wl2, Wr2, Wl3, Wr3, Cin, Hm, Cout, WT1, WT2, WT3,
      att1, att2, att3,
      b1, bn1g, bn1b, bn1m, bn1v,
      b2, bn2g, bn2b, bn2m, bn2v,
      a16_1, a16_2, a16_3, sc1, sh1, sc2, sh2);

  const int mb = (N + 127) / 128;
  const int gb = (N + 3) / 4;

  // --- layer 1 ---
  k_hgemm<<<dim3(mb, 2 * Hm / 256), 512, 0, stream>>>(x16, WT1, xlr, N, 2 * Hm, Cin);
  k_gat4<<<gb, 256, 0, stream>>>(xlr, a16_1, sc1, sh1, offs, csr, order, N, h);

  // --- layer 2 ---
  k_hgemm<<<dim3(mb, 2 * Hm / 256), 512, 0, stream>>>(h, WT2, xlr, N, 2 * Hm, Hm);
  k_gat4<<<gb, 256, 0, stream>>>(xlr, a16_2, sc2, sh2, offs, csr, order, N, h);

  // --- layer 3 ---
  k_hgemm<<<dim3(mb, 2 * Cout / 256), 512, 0, stream>>>(h, WT3, xlr, N, 2 * Cout, Hm);
  k_gat1<<<gb, 256, 0, stream>>>(xlr, a16_3, b3, offs, csr, order, N, (float*)d_out);
}

// Round 10
// 376.222 us; speedup vs baseline: 1.8601x; 1.8601x over previous
//
#include <hip/hip_runtime.h>
#include <math.h>

#define NEG_SLOPE 0.2f
#define BN_EPS 1e-5f
#define LOG2E 1.44269504f

typedef _Float16 f16x8 __attribute__((ext_vector_type(8)));
typedef float f32x4 __attribute__((ext_vector_type(4)));
typedef _Float16 h2 __attribute__((ext_vector_type(2)));

union F8 { f16x8 v; h2 h[4]; _Float16 s[8]; uint4 u; };

__device__ __forceinline__ void async_copy16(const void* g, void* l) {
  __builtin_amdgcn_global_load_lds(
      (const __attribute__((address_space(1))) void*)g,
      (__attribute__((address_space(3))) void*)l, 16, 0, 0);
}

__device__ __forceinline__ unsigned int pack2f(float a, float b) {
  union { unsigned int u; _Float16 h[2]; } c;
  c.h[0] = (_Float16)a; c.h[1] = (_Float16)b; return c.u;
}

__device__ __forceinline__ float fdot2f(h2 a, h2 b, float c) {
#if __has_builtin(__builtin_amdgcn_fdot2)
  return __builtin_amdgcn_fdot2(a, b, c, false);
#else
  return fmaf((float)a[0], (float)b[0], fmaf((float)a[1], (float)b[1], c));
#endif
}

// acc(f32) += p(f32) * fp16_half(u) -- pinned to a single v_fma_mix_f32.
#define FMAMIX_LO(a, p, u) \
  asm("v_fma_mix_f32 %0, %1, %2, %0 op_sel:[0,0,0] op_sel_hi:[0,1,0]" \
      : "+v"(a) : "v"(p), "v"(u))
#define FMAMIX_HI(a, p, u) \
  asm("v_fma_mix_f32 %0, %1, %2, %0 op_sel:[0,1,0] op_sel_hi:[0,1,0]" \
      : "+v"(a) : "v"(p), "v"(u))

// DPP butterfly add within quads (pure VALU, no LDS pipe).
template <int CTRL>
__device__ __forceinline__ float dpp_xadd(float x) {
  int yi = __builtin_amdgcn_mov_dpp(__builtin_bit_cast(int, x), CTRL, 0xF, 0xF, true);
  return x + __builtin_bit_cast(float, yi);
}

// ---------------- fused prep: f2h + weight transpose/concat + att/BN fold ------------
__global__ __launch_bounds__(256) void k_prep_all(
    const float* __restrict__ x, unsigned int* __restrict__ x16u, int n2,
    const float* __restrict__ Wl1, const float* __restrict__ Wr1,
    const float* __restrict__ Wl2, const float* __restrict__ Wr2,
    const float* __restrict__ Wl3, const float* __restrict__ Wr3,
    int Cin, int Hm, int Cout,
    _Float16* __restrict__ WT1, _Float16* __restrict__ WT2, _Float16* __restrict__ WT3,
    const float* __restrict__ att1, const float* __restrict__ att2, const float* __restrict__ att3,
    const float* __restrict__ b1, const float* __restrict__ g1, const float* __restrict__ bb1,
    const float* __restrict__ m1, const float* __restrict__ v1,
    const float* __restrict__ b2, const float* __restrict__ g2, const float* __restrict__ bb2,
    const float* __restrict__ m2, const float* __restrict__ v2,
    _Float16* __restrict__ a16_1, _Float16* __restrict__ a16_2, _Float16* __restrict__ a16_3,
    float* __restrict__ sc1, float* __restrict__ sh1,
    float* __restrict__ sc2, float* __restrict__ sh2) {
  int i = blockIdx.x * 256 + threadIdx.x;
  if (i < n2) {
    float2 v = reinterpret_cast<const float2*>(x)[i];
    x16u[i] = pack2f(v.x, v.y);
    return;
  }
  i -= n2;
  int w1 = 2 * Hm * Cin, w2 = 2 * Hm * Hm, w3 = 2 * Cout * Hm;
  if (i < w1) {
    int c = i / Cin, k = i % Cin;
    float v = (c < Hm) ? Wl1[(size_t)k * Hm + c] : Wr1[(size_t)k * Hm + (c - Hm)];
    WT1[i] = (_Float16)v;
    return;
  }
  i -= w1;
  if (i < w2) {
    int c = i / Hm, k = i % Hm;
    float v = (c < Hm) ? Wl2[(size_t)k * Hm + c] : Wr2[(size_t)k * Hm + (c - Hm)];
    WT2[i] = (_Float16)v;
    return;
  }
  i -= w2;
  if (i < w3) {
    int c = i / Hm, k = i % Hm;
    float v = (c < Cout) ? Wl3[(size_t)k * Cout + c] : Wr3[(size_t)k * Cout + (c - Cout)];
    WT3[i] = (_Float16)v;
    return;
  }
  i -= w3;
  if (i < 256) {
    int c = i;
    a16_1[c] = (_Float16)(att1[c] * LOG2E);
    a16_2[c] = (_Float16)(att2[c] * LOG2E);
    if (c < 128) a16_3[c] = (_Float16)(att3[c] * LOG2E);
    float s = g1[c] * rsqrtf(v1[c] + BN_EPS);
    sc1[c] = s; sh1[c] = (b1[c] - m1[c]) * s + bb1[c];
    s = g2[c] * rsqrtf(v2[c] + BN_EPS);
    sc2[c] = s; sh2[c] = (b2[c] - m2[c]) * s + bb2[c];
  }
}

// ---------------- CSR build (group edges by dst, self-loops appended) ----------------
__global__ void k_count(const int* __restrict__ ei, int E, int N, int* __restrict__ deg) {
  int e = blockIdx.x * blockDim.x + threadIdx.x;
  int T = E + N;
  if (e >= T) return;
  int d = (e < E) ? ei[E + e] : (e - E);
  atomicAdd(&deg[d], 1);
}

__global__ __launch_bounds__(256) void k_bsum(const int* __restrict__ deg, int N,
                                              int* __restrict__ bsum) {
  int t = threadIdx.x;
  int i = blockIdx.x * 256 + t;
  int v = (i < N) ? deg[i] : 0;
  #pragma unroll
  for (int off = 32; off > 0; off >>= 1) v += __shfl_xor(v, off, 64);
  __shared__ int ws[4];
  if ((t & 63) == 0) ws[t >> 6] = v;
  __syncthreads();
  if (t == 0) bsum[blockIdx.x] = ws[0] + ws[1] + ws[2] + ws[3];
}

__global__ __launch_bounds__(1024) void k_bscan(int* __restrict__ bsum, int nb, int N,
                                                int* __restrict__ offs) {
  int t = threadIdx.x;
  int lane = t & 63, w = t >> 6;
  int v = (t < nb) ? bsum[t] : 0;
  int val = v;
  #pragma unroll
  for (int off = 1; off < 64; off <<= 1) {
    int x = __shfl_up(val, off, 64);
    if (lane >= off) val += x;
  }
  __shared__ int ws[16];
  if (lane == 63) ws[w] = val;
  __syncthreads();
  if (w == 0) {
    int s = (lane < 16) ? ws[lane] : 0;
    #pragma unroll
    for (int off = 1; off < 16; off <<= 1) {
      int x = __shfl_up(s, off, 64);
      if (lane >= off) s += x;
    }
    if (lane < 16) ws[lane] = s;
  }
  __syncthreads();
  int excl = (w > 0 ? ws[w - 1] : 0) + val - v;
  if (t < nb) bsum[t] = excl;
  if (t == nb - 1) offs[N] = excl + v;
}

__global__ __launch_bounds__(256) void k_boffs(const int* __restrict__ deg, int N,
                                               const int* __restrict__ bpre,
                                               int* __restrict__ offs, int* __restrict__ cursor) {
  int t = threadIdx.x;
  int i = blockIdx.x * 256 + t;
  int lane = t & 63, w = t >> 6;
  int v = (i < N) ? deg[i] : 0;
  int val = v;
  #pragma unroll
  for (int off = 1; off < 64; off <<= 1) {
    int x = __shfl_up(val, off, 64);
    if (lane >= off) val += x;
  }
  __shared__ int ws[4];
  if (lane == 63) ws[w] = val;
  __syncthreads();
  int wo = 0;
  #pragma unroll
  for (int k = 0; k < 4; ++k) if (k < w) wo += ws[k];
  int excl = bpre[blockIdx.x] + wo + val - v;
  if (i < N) { offs[i] = excl; cursor[i] = excl; }
}

__global__ void k_scatter(const int* __restrict__ ei, int E, int N,
                          int* __restrict__ cursor, int* __restrict__ csr_src) {
  int e = blockIdx.x * blockDim.x + threadIdx.x;
  int T = E + N;
  if (e < 32) csr_src[T + e] = 0;  // sentinels for prefetch
  if (e >= T) return;
  int s, d;
  if (e < E) { s = ei[e]; d = ei[E + e]; } else { s = d = e - E; }
  int pos = atomicAdd(&cursor[d], 1);
  csr_src[pos] = s;
}

// ---------------- fp16 MFMA GEMM: C[M,Ntot] = A[M,K] @ BT[Ntot,K]^T ----------------
// 128x256 tile, BK=64, 512 threads (8 waves, 2x4 of 64x64). Counted-vmcnt pipeline.
__global__ __launch_bounds__(512) void k_hgemm(const _Float16* __restrict__ A,
                                               const _Float16* __restrict__ BT,
                                               _Float16* __restrict__ C,
                                               int M, int Ntot, int K) {
  __shared__ _Float16 As[2][128 * 64];
  __shared__ _Float16 Bs[2][256 * 64];
  const int t = threadIdx.x;
  const int lane = t & 63, w = t >> 6;
  const int wr = w >> 2, wc = w & 3;
  const int bm0 = blockIdx.x * 128, bn0 = blockIdx.y * 256;
  f32x4 acc[4][4] = {};
  const int nkt = K >> 6;

  auto stage = [&](int b, int kt) {
    #pragma unroll
    for (int i = 0; i < 2; ++i) {
      int q = i * 512 + t;                 // A: 1024 slots
      int row = q >> 3, sl = q & 7;
      int ssrc = sl ^ (row & 7);
      int ga = bm0 + row; if (ga >= M) ga = M - 1;
      async_copy16(&A[(size_t)ga * K + kt * 64 + ssrc * 8], &As[b][q * 8]);
    }
    #pragma unroll
    for (int i = 0; i < 4; ++i) {
      int q = i * 512 + t;                 // B: 2048 slots
      int row = q >> 3, sl = q & 7;
      int ssrc = sl ^ (row & 7);
      async_copy16(&BT[(size_t)(bn0 + row) * K + kt * 64 + ssrc * 8], &Bs[b][q * 8]);
    }
  };

  stage(0, 0);
  for (int kt = 0; kt < nkt; ++kt) {
    int cur = kt & 1;
    if (kt + 1 < nkt) {
      stage(cur ^ 1, kt + 1);
      asm volatile("s_waitcnt vmcnt(6)" ::: "memory");   // prev stage drained
    } else {
      asm volatile("s_waitcnt vmcnt(0)" ::: "memory");
    }
    __builtin_amdgcn_s_barrier();
    #pragma unroll
    for (int ks = 0; ks < 2; ++ks) {
      f16x8 a[4], b[4];
      const int sl = ks * 4 + (lane >> 4);
      #pragma unroll
      for (int mi = 0; mi < 4; ++mi) {
        int row = wr * 64 + mi * 16 + (lane & 15);
        a[mi] = *(const f16x8*)&As[cur][(row * 8 + (sl ^ (row & 7))) * 8];
      }
      #pragma unroll
      for (int ni = 0; ni < 4; ++ni) {
        int row = wc * 64 + ni * 16 + (lane & 15);
        b[ni] = *(const f16x8*)&Bs[cur][(row * 8 + (sl ^ (row & 7))) * 8];
      }
      #pragma unroll
      for (int mi = 0; mi < 4; ++mi)
        #pragma unroll
        for (int ni = 0; ni < 4; ++ni)
          acc[mi][ni] = __builtin_amdgcn_mfma_f32_16x16x32_f16(a[mi], b[ni], acc[mi][ni], 0, 0, 0);
    }
    __builtin_amdgcn_s_barrier();
  }
  const int r0 = (lane >> 4) * 4;
  const int cc = lane & 15;
  #pragma unroll
  for (int mi = 0; mi < 4; ++mi) {
    #pragma unroll
    for (int r = 0; r < 4; ++r) {
      int row = bm0 + wr * 64 + mi * 16 + r0 + r;
      if (row >= M) continue;
      #pragma unroll
      for (int ni = 0; ni < 4; ++ni) {
        int col = bn0 + wc * 64 + ni * 16 + cc;
        C[(size_t)row * Ntot + col] = (_Float16)acc[mi][ni][r];
      }
    }
  }
}

// ---------------- fused GATv2 edge phase, H=4, F=64 (Hm=256) ----------------
// 4 nodes / 256-thread block (1 wave/node); 16 ch/lane -> 4 edges/iteration;
// head = quad; 1-deep prefetch; exp2-domain online softmax; fma_mix accumulate.
__global__ __launch_bounds__(256) void k_gat4(
    const _Float16* __restrict__ xlr,      // [N][512]: xl|xr, row = 1024 B
    const _Float16* __restrict__ att16,    // [256], pre-scaled by log2e
    const float* __restrict__ sc, const float* __restrict__ sh,
    const int* __restrict__ offs, const int* __restrict__ csr,
    int N, _Float16* __restrict__ hout) {  // [N][256]
  const int n = blockIdx.x * 4 + (threadIdx.x >> 6);
  if (n >= N) return;
  const int lane = threadIdx.x & 63;
  const int sub = lane & 15;
  const int qi = lane >> 4;
  const unsigned subB = (unsigned)sub << 5;
  const char* __restrict__ xc = (const char*)xlr;

  F8 at0, at1, xr0, xr1;
  at0.u = *(const uint4*)((const char*)att16 + subB);
  at1.u = *(const uint4*)((const char*)att16 + subB + 16);
  {
    unsigned xro = (unsigned)n * 1024u + 512u + subB;
    xr0.u = *(const uint4*)(xc + xro);
    xr1.u = *(const uint4*)(xc + xro + 16);
  }
  const h2 k02 = {(_Float16)NEG_SLOPE, (_Float16)NEG_SLOPE};
  const int j0 = offs[n], j1 = offs[n + 1];

  float m = -INFINITY, l = 0.f;
  float acc[16];
  #pragma unroll
  for (int i = 0; i < 16; ++i) acc[i] = 0.f;

  unsigned oA = (unsigned)csr[j0 + qi] * 1024u + subB;
  unsigned oB = (unsigned)csr[j0 + 4 + qi] * 1024u + subB;
  F8 v0, v1;
  v0.u = *(const uint4*)(xc + oA);
  v1.u = *(const uint4*)(xc + oA + 16);

  for (int j = j0; j < j1; j += 4) {
    F8 n0, n1;
    n0.u = *(const uint4*)(xc + oB);          // prefetch next 4 edges
    n1.u = *(const uint4*)(xc + oB + 16);
    oB = (unsigned)csr[j + 8 + qi] * 1024u + subB;

    float e = 0.f;
    #pragma unroll
    for (int r = 0; r < 4; ++r) {
      h2 s0 = v0.h[r] + xr0.h[r];
      s0 = __builtin_elementwise_max(s0, s0 * k02);
      e = fdot2f(s0, at0.h[r], e);
      h2 s1 = v1.h[r] + xr1.h[r];
      s1 = __builtin_elementwise_max(s1, s1 * k02);
      e = fdot2f(s1, at1.h[r], e);
    }
    e = dpp_xadd<0xB1>(e);
    e = dpp_xadd<0x4E>(e);
    if (j + qi >= j1) e = -1e30f;             // tail mask

    if (__any(e > m + 11.5f)) {               // defer-max (log2 units)
      float mc = fmaxf(m, e);
      mc = fmaxf(mc, __shfl_xor(mc, 16, 64));
      mc = fmaxf(mc, __shfl_xor(mc, 32, 64));
      float c0 = exp2f(m - mc);
      l *= c0;
      #pragma unroll
      for (int i = 0; i < 16; ++i) acc[i] *= c0;
      m = mc;
    }
    float p = exp2f(e - m);
    l += p;
    FMAMIX_LO(acc[0],  p, v0.u.x); FMAMIX_HI(acc[1],  p, v0.u.x);
    FMAMIX_LO(acc[2],  p, v0.u.y); FMAMIX_HI(acc[3],  p, v0.u.y);
    FMAMIX_LO(acc[4],  p, v0.u.z); FMAMIX_HI(acc[5],  p, v0.u.z);
    FMAMIX_LO(acc[6],  p, v0.u.w); FMAMIX_HI(acc[7],  p, v0.u.w);
    FMAMIX_LO(acc[8],  p, v1.u.x); FMAMIX_HI(acc[9],  p, v1.u.x);
    FMAMIX_LO(acc[10], p, v1.u.y); FMAMIX_HI(acc[11], p, v1.u.y);
    FMAMIX_LO(acc[12], p, v1.u.z); FMAMIX_HI(acc[13], p, v1.u.z);
    FMAMIX_LO(acc[14], p, v1.u.w); FMAMIX_HI(acc[15], p, v1.u.w);
    v0 = n0; v1 = n1;
  }
  // merge quarters
  l += __shfl_xor(l, 16, 64);
  l += __shfl_xor(l, 32, 64);
  #pragma unroll
  for (int i = 0; i < 16; ++i) {
    acc[i] += __shfl_xor(acc[i], 16, 64);
    acc[i] += __shfl_xor(acc[i], 32, 64);
  }
  if (qi == 0) {
    float inv = 1.f / l;
    const float4* sc4 = (const float4*)sc;
    const float4* sh4 = (const float4*)sh;
    float ov[16];
    #pragma unroll
    for (int k = 0; k < 4; ++k) {
      float4 s4 = sc4[4 * sub + k], t4 = sh4[4 * sub + k];
      ov[4 * k + 0] = acc[4 * k + 0] * inv * s4.x + t4.x;
      ov[4 * k + 1] = acc[4 * k + 1] * inv * s4.y + t4.y;
      ov[4 * k + 2] = acc[4 * k + 2] * inv * s4.z + t4.z;
      ov[4 * k + 3] = acc[4 * k + 3] * inv * s4.w + t4.w;
    }
    #pragma unroll
    for (int i = 0; i < 16; ++i) ov[i] = ov[i] > 0.f ? ov[i] : (__expf(ov[i]) - 1.f);
    F8 o0h, o1h;
    #pragma unroll
    for (int i = 0; i < 8; ++i) { o0h.s[i] = (_Float16)ov[i]; o1h.s[i] = (_Float16)ov[8 + i]; }
    F8* ob = (F8*)hout;
    ob[(size_t)n * 32 + 2 * sub] = o0h;
    ob[(size_t)n * 32 + 2 * sub + 1] = o1h;
  }
}

// ---------------- fused GATv2 edge phase, H=1, F=128 (layer 3) — CONTROL (unchanged) --
__global__ __launch_bounds__(256) void k_gat1(
    const _Float16* __restrict__ xlr,      // [N][256]: xl|xr, row = 512 B
    const _Float16* __restrict__ att16,    // [128], pre-scaled by log2e
    const float* __restrict__ bias,        // [128]
    const int* __restrict__ offs, const int* __restrict__ csr,
    int N, float* __restrict__ out) {      // [N][128] fp32
  const int n = blockIdx.x * 4 + (threadIdx.x >> 6);
  if (n >= N) return;
  const int lane = threadIdx.x & 63;
  const int sub = lane & 7;
  const int gi = lane >> 3;
  const unsigned subB = (unsigned)sub << 5;
  const char* __restrict__ xc = (const char*)xlr;

  F8 at0, at1, xr0, xr1;
  at0.u = *(const uint4*)((const char*)att16 + subB);
  at1.u = *(const uint4*)((const char*)att16 + subB + 16);
  {
    unsigned xro = (unsigned)n * 512u + 256u + subB;
    xr0.u = *(const uint4*)(xc + xro);
    xr1.u = *(const uint4*)(xc + xro + 16);
  }
  const h2 k02 = {(_Float16)NEG_SLOPE, (_Float16)NEG_SLOPE};
  const int j0 = offs[n], j1 = offs[n + 1];

  float m = -INFINITY, l = 0.f;
  float acc[16];
  #pragma unroll
  for (int i = 0; i < 16; ++i) acc[i] = 0.f;

  unsigned oA = (unsigned)csr[j0 + gi] * 512u + subB;
  unsigned oB = (unsigned)csr[j0 + 8 + gi] * 512u + subB;
  F8 v0, v1;
  v0.u = *(const uint4*)(xc + oA);
  v1.u = *(const uint4*)(xc + oA + 16);

  for (int j = j0; j < j1; j += 8) {
    F8 n0, n1;
    n0.u = *(const uint4*)(xc + oB);
    n1.u = *(const uint4*)(xc + oB + 16);
    oB = (unsigned)csr[j + 16 + gi] * 512u + subB;

    float e = 0.f;
    #pragma unroll
    for (int r = 0; r < 4; ++r) {
      h2 s0 = v0.h[r] + xr0.h[r];
      s0 = __builtin_elementwise_max(s0, s0 * k02);
      e = fdot2f(s0, at0.h[r], e);
      h2 s1 = v1.h[r] + xr1.h[r];
      s1 = __builtin_elementwise_max(s1, s1 * k02);
      e = fdot2f(s1, at1.h[r], e);
    }
    e = dpp_xadd<0xB1>(e);
    e = dpp_xadd<0x4E>(e);
    e += __shfl_xor(e, 4, 64);
    if (j + gi >= j1) e = -1e30f;

    if (__any(e > m + 11.5f)) {
      float mc = fmaxf(m, e);
      mc = fmaxf(mc, __shfl_xor(mc, 8, 64));
      mc = fmaxf(mc, __shfl_xor(mc, 16, 64));
      mc = fmaxf(mc, __shfl_xor(mc, 32, 64));
      float c0 = exp2f(m - mc);
      l *= c0;
      #pragma unroll
      for (int i = 0; i < 16; ++i) acc[i] *= c0;
      m = mc;
    }
    float p = exp2f(e - m);
    l += p;
    #pragma unroll
    for (int i = 0; i < 8; ++i) acc[i] = fmaf(p, (float)v0.s[i], acc[i]);
    #pragma unroll
    for (int i = 0; i < 8; ++i) acc[8 + i] = fmaf(p, (float)v1.s[i], acc[8 + i]);
    v0 = n0; v1 = n1;
  }
  l += __shfl_xor(l, 8, 64);
  l += __shfl_xor(l, 16, 64);
  l += __shfl_xor(l, 32, 64);
  #pragma unroll
  for (int i = 0; i < 16; ++i) {
    acc[i] += __shfl_xor(acc[i], 8, 64);
    acc[i] += __shfl_xor(acc[i], 16, 64);
    acc[i] += __shfl_xor(acc[i], 32, 64);
  }
  if (gi == 0) {
    float inv = 1.f / l;
    const float4* b4 = (const float4*)bias;
    float4* ob = (float4*)out;
    #pragma unroll
    for (int k = 0; k < 4; ++k) {
      float4 bb = b4[4 * sub + k];
      float4 o;
      o.x = acc[4 * k + 0] * inv + bb.x;
      o.y = acc[4 * k + 1] * inv + bb.y;
      o.z = acc[4 * k + 2] * inv + bb.z;
      o.w = acc[4 * k + 3] * inv + bb.w;
      ob[(size_t)n * 32 + 4 * sub + k] = o;
    }
  }
}

extern "C" void kernel_launch(void* const* d_in, const int* in_sizes, int n_in,
                              void* d_out, int out_size, void* d_ws, size_t ws_size,
                              hipStream_t stream) {
  const float* x    = (const float*)d_in[0];
  const int*   ei   = (const int*)d_in[1];
  const float* Wl1  = (const float*)d_in[2];
  const float* Wr1  = (const float*)d_in[3];
  const float* att1 = (const float*)d_in[4];
  const float* b1   = (const float*)d_in[5];
  const float* bn1g = (const float*)d_in[6];
  const float* bn1b = (const float*)d_in[7];
  const float* bn1m = (const float*)d_in[8];
  const float* bn1v = (const float*)d_in[9];
  const float* Wl2  = (const float*)d_in[10];
  const float* Wr2  = (const float*)d_in[11];
  const float* att2 = (const float*)d_in[12];
  const float* b2   = (const float*)d_in[13];
  const float* bn2g = (const float*)d_in[14];
  const float* bn2b = (const float*)d_in[15];
  const float* bn2m = (const float*)d_in[16];
  const float* bn2v = (const float*)d_in[17];
  const float* Wl3  = (const float*)d_in[18];
  const float* Wr3  = (const float*)d_in[19];
  const float* att3 = (const float*)d_in[20];
  const float* b3   = (const float*)d_in[21];

  const int Hm   = in_sizes[5];          // 256
  const int Cout = in_sizes[21];         // 128
  const int Cin  = in_sizes[2] / Hm;     // 128
  const int N    = in_sizes[0] / Cin;    // 50000
  const int E    = in_sizes[1] / 2;      // 800000
  const int T    = E + N;

  _Float16* x16 = (_Float16*)d_ws;                 // N*Cin
  _Float16* h   = x16 + (size_t)N * Cin;           // N*Hm
  _Float16* xlr = h + (size_t)N * Hm;              // N*2*Hm
  _Float16* WT1 = xlr + (size_t)N * 2 * Hm;        // (2*Hm)*Cin
  _Float16* WT2 = WT1 + (size_t)2 * Hm * Cin;      // (2*Hm)*Hm
  _Float16* WT3 = WT2 + (size_t)2 * Hm * Hm;       // (2*Cout)*Hm
  _Float16* a16_1 = WT3 + (size_t)2 * Cout * Hm;   // 256
  _Float16* a16_2 = a16_1 + 256;                   // 256
  _Float16* a16_3 = a16_2 + 256;                   // 128
  float* sc1 = (float*)(a16_3 + 128);              // 256
  float* sh1 = sc1 + 256;
  float* sc2 = sh1 + 256;
  float* sh2 = sc2 + 256;
  int* deg    = (int*)(sh2 + 256);                 // N
  int* offs   = deg + N;                           // N+1
  int* cursor = offs + N + 1;                      // N
  int* csr    = cursor + N;                        // T+32 (sentinels)
  int* bsum   = csr + T + 32;                      // nb

  const int nb = (N + 255) / 256;

  // --- CSR build by dst (hierarchical scan) ---
  hipMemsetAsync(deg, 0, (size_t)N * sizeof(int), stream);
  k_count<<<(T + 255) / 256, 256, 0, stream>>>(ei, E, N, deg);
  k_bsum<<<nb, 256, 0, stream>>>(deg, N, bsum);
  k_bscan<<<1, 1024, 0, stream>>>(bsum, nb, N, offs);
  k_boffs<<<nb, 256, 0, stream>>>(deg, N, bsum, offs, cursor);
  k_scatter<<<(T + 255) / 256, 256, 0, stream>>>(ei, E, N, cursor, csr);

  // --- fused prep: x->fp16, weights->fp16 transposed concat, att/BN folds ---
  int n2 = N * Cin / 2;
  int wtot = 2 * Hm * Cin + 2 * Hm * Hm + 2 * Cout * Hm;
  int ptot = n2 + wtot + 256;
  k_prep_all<<<(ptot + 255) / 256, 256, 0, stream>>>(
      x, (unsigned int*)x16, n2,
      Wl1, Wr1, Wl2, Wr2, Wl3, Wr3, Cin, Hm, Cout, WT1, WT2, WT3,
      att1, att2, att3,
      b1, bn1g, bn1b, bn1m, bn1v,
      b2, bn2g, bn2b, bn2m, bn2v,
      a16_1, a16_2, a16_3, sc1, sh1, sc2, sh2);

  const int mb = (N + 127) / 128;
  const int gb = (N + 3) / 4;

  // --- layer 1 ---
  k_hgemm<<<dim3(mb, 2 * Hm / 256), 512, 0, stream>>>(x16, WT1, xlr, N, 2 * Hm, Cin);
  k_gat4<<<gb, 256, 0, stream>>>(xlr, a16_1, sc1, sh1, offs, csr, N, h);

  // --- layer 2 ---
  k_hgemm<<<dim3(mb, 2 * Hm / 256), 512, 0, stream>>>(h, WT2, xlr, N, 2 * Hm, Hm);
  k_gat4<<<gb, 256, 0, stream>>>(xlr, a16_2, sc2, sh2, offs, csr, N, h);

  // --- layer 3 ---
  k_hgemm<<<dim3(mb, 2 * Cout / 256), 512, 0, stream>>>(h, WT3, xlr, N, 2 * Cout, Hm);
  k_gat1<<<gb, 256, 0, stream>>>(xlr, a16_3, b3, offs, csr, N, (float*)d_out);
}